// Round 2
// baseline (271.312 us; speedup 1.0000x reference)
//
#include <hip/hip_runtime.h>
#include <hip/hip_bf16.h>

typedef __bf16 bf16x8 __attribute__((ext_vector_type(8)));
typedef float f32x4 __attribute__((ext_vector_type(4)));
typedef unsigned short u16x8 __attribute__((ext_vector_type(8)));

__device__ __forceinline__ unsigned short f2bf(float f) {
    unsigned int u = __builtin_bit_cast(unsigned int, f);
    unsigned int r = (u + 0x7FFFu + ((u >> 16) & 1u)) >> 16;
    return (unsigned short)r;
}

__device__ __forceinline__ void load_lds_16(const void* g, void* lds) {
    __builtin_amdgcn_global_load_lds(
        (const __attribute__((address_space(1))) unsigned int*)g,
        (__attribute__((address_space(3))) unsigned int*)lds, 16, 0, 0);
}

// ---------- 1) x fp32 -> bf16 ----------
__global__ void conv_x_kernel(const float* __restrict__ x, unsigned short* __restrict__ xb) {
    int i = blockIdx.x * 256 + threadIdx.x;   // 8 elems/thread
    const float4* xp = (const float4*)x;
    float4 a = xp[i * 2];
    float4 c = xp[i * 2 + 1];
    u16x8 r;
    r[0] = f2bf(a.x); r[1] = f2bf(a.y); r[2] = f2bf(a.z); r[3] = f2bf(a.w);
    r[4] = f2bf(c.x); r[5] = f2bf(c.y); r[6] = f2bf(c.z); r[7] = f2bf(c.w);
    *(u16x8*)(xb + (size_t)i * 8) = r;
}

// ---------- 2) WeffB bf16[o][k] = W + 2*B@A ----------
__global__ void weffB_kernel(const float* __restrict__ W, const float* __restrict__ A,
                             const float* __restrict__ B, unsigned short* __restrict__ WeffB) {
    int o = blockIdx.x / 3;
    int k = (blockIdx.x % 3) * 256 + threadIdx.x;
    float acc = W[o * 768 + k];
#pragma unroll
    for (int r = 0; r < 8; ++r) acc += 2.0f * B[o * 8 + r] * A[r * 768 + k];
    WeffB[o * 768 + k] = f2bf(acc);
}

// fallback fp32 version
__global__ void weff_kernel(const float* __restrict__ W, const float* __restrict__ A,
                            const float* __restrict__ B, float* __restrict__ Weff) {
    int o = blockIdx.x / 3;
    int k = (blockIdx.x % 3) * 256 + threadIdx.x;
    float acc = W[o * 768 + k];
#pragma unroll
    for (int r = 0; r < 8; ++r) acc += 2.0f * B[o * 8 + r] * A[r * 768 + k];
    Weff[o * 768 + k] = acc;
}

// ---------- 3) wq = h @ Wl^T : wave-per-output, 24576 blocks ----------
__global__ void wq2_kernel(const float* __restrict__ uh, const float* __restrict__ ih,
                           const float* __restrict__ Wu, const float* __restrict__ Wi,
                           float* __restrict__ wqu, float* __restrict__ wqi) {
    int bx = blockIdx.x;                  // og(192) x b(64) x br(2)
    int og = bx % 192;
    int rest = bx / 192;
    int b = rest & 63;
    int br = rest >> 6;
    int wave = threadIdx.x >> 6, lane = threadIdx.x & 63;
    int o = og * 4 + wave;
    const float* h = (br ? ih : uh) + b * 768;
    const float* Wrow = (br ? Wi : Wu) + (size_t)o * 768;
    const float4* hp = (const float4*)(h + lane * 12);
    const float4* wp = (const float4*)(Wrow + lane * 12);
    float s = 0.0f;
#pragma unroll
    for (int j = 0; j < 3; ++j) {
        float4 hv = hp[j], wv = wp[j];
        s += hv.x * wv.x + hv.y * wv.y + hv.z * wv.z + hv.w * wv.w;
    }
#pragma unroll
    for (int off = 32; off; off >>= 1) s += __shfl_down(s, off);
    if (lane == 0) (br ? wqi : wqu)[b * 768 + o] = s;
}

// ---------- 4) kron + bias: out[b,s,l*32+m] = bias + sum_q wq[b,q,l]*(sum_n x[b,s,q*24+n]*V[n,m]) ----------
// 4 rows per block; t exchanged via LDS; user/item interleaved as float2.
__global__ __launch_bounds__(256, 2) void kron_kernel(
    const float* __restrict__ x, const float* __restrict__ VU, const float* __restrict__ VI,
    const float* __restrict__ wqu, const float* __restrict__ wqi,
    const float* __restrict__ bias, float* __restrict__ out) {
    __shared__ __align__(16) float xs[4 * 768];       // 12 KB
    __shared__ __align__(16) float vui[24 * 32 * 2];  // 6 KB [n][m][2]
    __shared__ __align__(16) float tui[4 * 32 * 32 * 2]; // 32 KB [r][q][m][2]
    __shared__ __align__(16) float wqui[32 * 24 * 2]; // 6 KB [q][l][2]
    const int t = threadIdx.x;
    const int bs0 = blockIdx.x * 4;        // first row (b*256+s)
    const int b = bs0 >> 8;

#pragma unroll
    for (int r = 0; r < 4; ++r)
        for (int i = t; i < 768; i += 256) xs[r * 768 + i] = x[(size_t)(bs0 + r) * 768 + i];
    for (int i = t; i < 768; i += 256) {
        vui[i * 2] = VU[i];  vui[i * 2 + 1] = VI[i];
        wqui[i * 2] = wqu[b * 768 + i];  wqui[i * 2 + 1] = wqi[b * 768 + i];
    }
    __syncthreads();

    // step1: thread -> q = t>>3, m0 = (t&7)*4; all 4 rows, 4 m's
    {
        const int q = t >> 3, m0 = (t & 7) * 4;
        float2 acc1[4][4];
#pragma unroll
        for (int r = 0; r < 4; ++r)
#pragma unroll
            for (int mj = 0; mj < 4; ++mj) acc1[r][mj] = make_float2(0.f, 0.f);
        const int xb0 = q * 24;
#pragma unroll
        for (int n = 0; n < 24; ++n) {
            const float4 va = *(const float4*)&vui[(n * 32 + m0) * 2];       // m0,m0+1 (u,i)
            const float4 vb = *(const float4*)&vui[(n * 32 + m0 + 2) * 2];   // m0+2,m0+3
#pragma unroll
            for (int r = 0; r < 4; ++r) {
                float xv = xs[r * 768 + xb0 + n];
                acc1[r][0].x += xv * va.x; acc1[r][0].y += xv * va.y;
                acc1[r][1].x += xv * va.z; acc1[r][1].y += xv * va.w;
                acc1[r][2].x += xv * vb.x; acc1[r][2].y += xv * vb.y;
                acc1[r][3].x += xv * vb.z; acc1[r][3].y += xv * vb.w;
            }
        }
#pragma unroll
        for (int r = 0; r < 4; ++r) {
            float* dst = &tui[((r << 10) + (q << 5) + m0) * 2];
            *(float4*)dst = make_float4(acc1[r][0].x, acc1[r][0].y, acc1[r][1].x, acc1[r][1].y);
            *(float4*)(dst + 4) = make_float4(acc1[r][2].x, acc1[r][2].y, acc1[r][3].x, acc1[r][3].y);
        }
    }
    __syncthreads();

    // step2: thread -> m = t&31, l = (t>>5) + 8k (k=0..2); outputs o = t + 256k
    {
        const int m = t & 31, l0 = t >> 5;
        float acc2[4][3];
#pragma unroll
        for (int r = 0; r < 4; ++r)
#pragma unroll
            for (int k = 0; k < 3; ++k) acc2[r][k] = 0.f;
#pragma unroll 8
        for (int q = 0; q < 32; ++q) {
            const float2 w0 = *(const float2*)&wqui[(q * 24 + l0) * 2];
            const float2 w1 = *(const float2*)&wqui[(q * 24 + l0 + 8) * 2];
            const float2 w2 = *(const float2*)&wqui[(q * 24 + l0 + 16) * 2];
#pragma unroll
            for (int r = 0; r < 4; ++r) {
                const float2 tv = *(const float2*)&tui[((r << 10) + (q << 5) + m) * 2];
                acc2[r][0] += tv.x * w0.x + tv.y * w0.y;
                acc2[r][1] += tv.x * w1.x + tv.y * w1.y;
                acc2[r][2] += tv.x * w2.x + tv.y * w2.y;
            }
        }
        float bv0 = bias[t], bv1 = bias[t + 256], bv2 = bias[t + 512];
#pragma unroll
        for (int r = 0; r < 4; ++r) {
            float* op = out + (size_t)(bs0 + r) * 768;
            op[t] = acc2[r][0] + bv0;
            op[t + 256] = acc2[r][1] + bv1;
            op[t + 512] = acc2[r][2] + bv2;
        }
    }
}

// ---------- 5) out += xb @ WeffB^T : shared-weight MFMA GEMM, RMW epilogue ----------
__global__ __launch_bounds__(256, 2) void gemm_add_kernel(
    const unsigned short* __restrict__ Xb, const unsigned short* __restrict__ WeffB,
    float* __restrict__ out) {
    __shared__ __align__(16) unsigned short As[128 * 64];
    __shared__ __align__(16) unsigned short Bs[128 * 64];
    const int tid = threadIdx.x;
    const int wave = tid >> 6, lane = tid & 63;
    const int b = blockIdx.z, mt = blockIdx.y, nt = blockIdx.x;
    const int s0 = mt * 128, n0 = nt * 128;
    const unsigned short* Ab = Xb + (size_t)(b * 256 + s0) * 768;
    const unsigned short* Bb = WeffB + (size_t)n0 * 768;
    const int wm = wave & 1, wn = wave >> 1;

    f32x4 acc[4][4] = {};

    const int lrow = lane >> 3;
    const int lcp = lane & 7;

    for (int kk = 0; kk < 768; kk += 64) {
#pragma unroll
        for (int u = 0; u < 4; ++u) {
            int tA = wave * 4 + u;
            int r = tA * 8 + lrow;
            int c = lcp ^ (r & 7);
            load_lds_16(Ab + (size_t)r * 768 + kk + c * 8, (void*)(As + tA * 512));
            load_lds_16(Bb + (size_t)r * 768 + kk + c * 8, (void*)(Bs + tA * 512));
        }
        __syncthreads();
#pragma unroll
        for (int h = 0; h < 2; ++h) {
            const int cb = h * 4 + (lane >> 4);
            const int rl = lane & 15;
            bf16x8 af[4], bfr[4];
#pragma unroll
            for (int i = 0; i < 4; ++i) {
                int r = wm * 64 + i * 16 + rl;
                int c = cb ^ (r & 7);
                af[i] = *(const bf16x8*)(As + r * 64 + c * 8);
            }
#pragma unroll
            for (int j = 0; j < 4; ++j) {
                int r = wn * 64 + j * 16 + rl;
                int c = cb ^ (r & 7);
                bfr[j] = *(const bf16x8*)(Bs + r * 64 + c * 8);
            }
#pragma unroll
            for (int i = 0; i < 4; ++i)
#pragma unroll
                for (int j = 0; j < 4; ++j)
                    acc[i][j] = __builtin_amdgcn_mfma_f32_16x16x32_bf16(af[i], bfr[j], acc[i][j], 0, 0, 0);
        }
        __syncthreads();
    }

    const int cl = lane & 15, rq = lane >> 4;
#pragma unroll
    for (int j = 0; j < 4; ++j) {
        int n = n0 + wn * 64 + j * 16 + cl;
#pragma unroll
        for (int i = 0; i < 4; ++i) {
            int mrow = s0 + wm * 64 + i * 16 + rq * 4;
            float* op = out + (size_t)(b * 256 + mrow) * 768 + n;
#pragma unroll
            for (int g = 0; g < 4; ++g) op[(size_t)g * 768] += acc[i][j][g];
        }
    }
}

// ---------- fallback (small ws): naive fp32 ----------
__global__ void naive_kernel(const float* __restrict__ x, const float* __restrict__ Weff,
                             const float* __restrict__ wqu, const float* __restrict__ wqi,
                             const float* __restrict__ VU, const float* __restrict__ VI,
                             const float* __restrict__ bias, float* __restrict__ out) {
    int bs_ = blockIdx.x / 3;
    int chunk = blockIdx.x % 3;
    int b = bs_ >> 8;
    __shared__ float xs[768];
    for (int i = threadIdx.x; i < 768; i += 256) xs[i] = x[(size_t)bs_ * 768 + i];
    __syncthreads();
    int o = chunk * 256 + threadIdx.x;
    int m = o & 31, l = o >> 5;
    float acc = bias[o];
    for (int q = 0; q < 32; ++q) {
        float wu = wqu[b * 768 + q * 24 + l];
        float wi = wqi[b * 768 + q * 24 + l];
#pragma unroll
        for (int n = 0; n < 24; ++n) {
            int k = q * 24 + n;
            float w = Weff[o * 768 + k] + VU[n * 32 + m] * wu + VI[n * 32 + m] * wi;
            acc += xs[k] * w;
        }
    }
    out[(size_t)bs_ * 768 + o] = acc;
}

extern "C" void kernel_launch(void* const* d_in, const int* in_sizes, int n_in,
                              void* d_out, int out_size, void* d_ws, size_t ws_size,
                              hipStream_t stream) {
    const float* x  = (const float*)d_in[0];
    const float* uh = (const float*)d_in[1];
    const float* ih = (const float*)d_in[2];
    const float* W  = (const float*)d_in[3];
    const float* bv = (const float*)d_in[4];
    const float* A  = (const float*)d_in[5];
    const float* B  = (const float*)d_in[6];
    const float* Wu = (const float*)d_in[7];
    const float* VU = (const float*)d_in[8];
    const float* Wi = (const float*)d_in[9];
    const float* VI = (const float*)d_in[10];
    float* out = (float*)d_out;

    const size_t off_xb   = 0;                        // 25,165,824 B
    const size_t off_weff = 25165824;                 // 1,179,648 B (bf16)
    const size_t off_wqu  = off_weff + 1179648;       // 196,608 B
    const size_t off_wqi  = off_wqu + 196608;
    const size_t need     = off_wqi + 196608;         // ~26.7 MB

    char* ws = (char*)d_ws;
    if (ws_size >= need) {
        unsigned short* xb    = (unsigned short*)(ws + off_xb);
        unsigned short* weffB = (unsigned short*)(ws + off_weff);
        float* wqu = (float*)(ws + off_wqu);
        float* wqi = (float*)(ws + off_wqi);
        conv_x_kernel<<<6144, 256, 0, stream>>>(x, xb);
        weffB_kernel<<<2304, 256, 0, stream>>>(W, A, B, weffB);
        wq2_kernel<<<24576, 256, 0, stream>>>(uh, ih, Wu, Wi, wqu, wqi);
        kron_kernel<<<4096, 256, 0, stream>>>(x, VU, VI, wqu, wqi, bv, out);
        gemm_add_kernel<<<dim3(6, 2, 64), 256, 0, stream>>>(xb, weffB, out);
    } else {
        float* weff = (float*)ws;
        float* wqu  = weff + 589824;
        float* wqi  = wqu + 49152;
        weff_kernel<<<2304, 256, 0, stream>>>(W, A, B, weff);
        wq2_kernel<<<24576, 256, 0, stream>>>(uh, ih, Wu, Wi, wqu, wqi);
        naive_kernel<<<49152, 256, 0, stream>>>(x, weff, wqu, wqi, VU, VI, bv, out);
    }
}

// Round 3
// 210.521 us; speedup vs baseline: 1.2888x; 1.2888x over previous
//
#include <hip/hip_runtime.h>
#include <hip/hip_bf16.h>

typedef __bf16 bf16x8 __attribute__((ext_vector_type(8)));
typedef float f32x4 __attribute__((ext_vector_type(4)));
typedef unsigned short u16x8 __attribute__((ext_vector_type(8)));
typedef unsigned short u16x4 __attribute__((ext_vector_type(4)));

__device__ __forceinline__ unsigned short f2bf(float f) {
    unsigned int u = __builtin_bit_cast(unsigned int, f);
    unsigned int r = (u + 0x7FFFu + ((u >> 16) & 1u)) >> 16;
    return (unsigned short)r;
}

__device__ __forceinline__ u16x8 zero8() {
    u16x8 v;
#pragma unroll
    for (int j = 0; j < 8; ++j) v[j] = 0;
    return v;
}

__device__ __forceinline__ void load_lds_16(const void* g, void* lds) {
    __builtin_amdgcn_global_load_lds(
        (const __attribute__((address_space(1))) unsigned int*)g,
        (__attribute__((address_space(3))) unsigned int*)lds, 16, 0, 0);
}

// ---------- prep: fused conv_x (bx<6144) + weffB (bx<8448) + wq (rest) ----------
__global__ void prep_kernel(const float* __restrict__ x, unsigned short* __restrict__ xb,
                            const float* __restrict__ W, const float* __restrict__ A,
                            const float* __restrict__ B, unsigned short* __restrict__ weffB,
                            const float* __restrict__ uh, const float* __restrict__ ih,
                            const float* __restrict__ Wu, const float* __restrict__ Wi,
                            float* __restrict__ wqu, float* __restrict__ wqi) {
    int bx = blockIdx.x;
    int t = threadIdx.x;
    if (bx < 6144) {
        // x fp32 -> bf16, 8 elems/thread
        int i = bx * 256 + t;
        const float4* xp = (const float4*)x;
        float4 a = xp[i * 2];
        float4 c = xp[i * 2 + 1];
        u16x8 r;
        r[0] = f2bf(a.x); r[1] = f2bf(a.y); r[2] = f2bf(a.z); r[3] = f2bf(a.w);
        r[4] = f2bf(c.x); r[5] = f2bf(c.y); r[6] = f2bf(c.z); r[7] = f2bf(c.w);
        *(u16x8*)(xb + (size_t)i * 8) = r;
    } else if (bx < 8448) {
        int idx = bx - 6144;
        int o = idx / 3;
        int k = (idx % 3) * 256 + t;
        float acc = W[o * 768 + k];
#pragma unroll
        for (int r = 0; r < 8; ++r) acc += 2.0f * B[o * 8 + r] * A[r * 768 + k];
        weffB[o * 768 + k] = f2bf(acc);
    } else {
        int b2 = bx - 8448;                 // 24576 blocks: og(192) x b(64) x br(2)
        int og = b2 % 192;
        int rest = b2 / 192;
        int b = rest & 63;
        int br = rest >> 6;
        int wave = t >> 6, lane = t & 63;
        int o = og * 4 + wave;
        const float* h = (br ? ih : uh) + b * 768;
        const float* Wrow = (br ? Wi : Wu) + (size_t)o * 768;
        const float4* hp = (const float4*)(h + lane * 12);
        const float4* wp = (const float4*)(Wrow + lane * 12);
        float s = 0.0f;
#pragma unroll
        for (int j = 0; j < 3; ++j) {
            float4 hv = hp[j], wv = wp[j];
            s += hv.x * wv.x + hv.y * wv.y + hv.z * wv.z + hv.w * wv.w;
        }
#pragma unroll
        for (int off = 32; off; off >>= 1) s += __shfl_down(s, off);
        if (lane == 0) (br ? wqi : wqu)[b * 768 + o] = s;
    }
}

// ---------- kron via MFMA: out[b,s,l*32+m] = bias + sum_{br,q} wq_br[b,q,l] * t_br[s,q,m] ----------
// per block: 4 s-rows. step1: t=(X4@V) M=128(r,q) K=32(n pad24) N=64(br,m);
// transpose t via LDS; step2: M=32(l pad24) K=64(br,q) N=128(r,m); coalesced stores.
__global__ __launch_bounds__(256, 3) void kron_kernel(
    const unsigned short* __restrict__ xb, const float* __restrict__ VU,
    const float* __restrict__ VI, const float* __restrict__ wqu,
    const float* __restrict__ wqi, const float* __restrict__ bias,
    float* __restrict__ out) {
    __shared__ __align__(16) unsigned short a1[128 * 40];  // [(r,q)][n]  10 KB
    __shared__ __align__(16) unsigned short b1[64 * 40];   // [(br,m)][n]  5 KB
    __shared__ __align__(16) unsigned short a2[32 * 72];   // [l][(br,q)]  4.5 KB
    __shared__ __align__(16) unsigned short bt[128 * 72];  // [(r,m)][(br,q)] 18 KB
    __shared__ float bias_s[768];
    const int t = threadIdx.x;
    const int wave = t >> 6, lane = t & 63;
    const int quad = lane >> 4, l15 = lane & 15;
    const int bs0 = blockIdx.x * 4;
    const int b = bs0 >> 8;

    // ---- staging ----
    // a1: 128 rows x (3 data chunks + 1 zero chunk of 8 bf16)
#pragma unroll
    for (int c0 = 0; c0 < 2; ++c0) {
        int c = t + c0 * 256;
        int rr = c >> 2, part = c & 3;
        u16x8 v = zero8();
        if (part < 3)
            v = *(const u16x8*)(xb + (size_t)(bs0 + (rr >> 5)) * 768 + (rr & 31) * 24 + part * 8);
        *(u16x8*)(a1 + rr * 40 + part * 8) = v;
    }
    // b1: V bf16, cols (br,m), k=n (zero pad n=24..31)
    {
        int col = t >> 2, kg = t & 3;
        int br = col >> 5, m = col & 31;
        const float* V = br ? VI : VU;
        u16x8 v = zero8();
        if (kg < 3) {
#pragma unroll
            for (int j = 0; j < 8; ++j) v[j] = f2bf(V[(kg * 8 + j) * 32 + m]);
        }
        *(u16x8*)(b1 + col * 40 + kg * 8) = v;
    }
    // a2: wq bf16, rows l (zero for l>=24), k=(br,q)
    {
        int row = t >> 3, kg = t & 7;
        u16x8 v = zero8();
        if (row < 24) {
#pragma unroll
            for (int j = 0; j < 8; ++j) {
                int k = kg * 8 + j;
                int br = k >> 5, q = k & 31;
                const float* wq = br ? wqi : wqu;
                v[j] = f2bf(wq[b * 768 + q * 24 + row]);
            }
        }
        *(u16x8*)(a2 + row * 72 + kg * 8) = v;
    }
    for (int i = t; i < 768; i += 256) bias_s[i] = bias[i];
    __syncthreads();

    // ---- step1 MFMA: D1[(r,q)][(br,m)] ----
    {
        f32x4 c1[2][4] = {};
        const int mtb = wave * 2;
        bf16x8 afr[2], bfr[4];
#pragma unroll
        for (int i = 0; i < 2; ++i)
            afr[i] = *(const bf16x8*)(a1 + ((mtb + i) * 16 + l15) * 40 + quad * 8);
#pragma unroll
        for (int j = 0; j < 4; ++j)
            bfr[j] = *(const bf16x8*)(b1 + (j * 16 + l15) * 40 + quad * 8);
#pragma unroll
        for (int i = 0; i < 2; ++i)
#pragma unroll
            for (int j = 0; j < 4; ++j)
                c1[i][j] = __builtin_amdgcn_mfma_f32_16x16x32_bf16(afr[i], bfr[j], c1[i][j], 0, 0, 0);
        // transpose to bt[(r,m)][(br,q)], bf16, b64 writes (g-packed along q)
#pragma unroll
        for (int i = 0; i < 2; ++i) {
            int mt = mtb + i;
            int r = mt >> 1;
            int q0 = (mt & 1) * 16 + quad * 4;
#pragma unroll
            for (int j = 0; j < 4; ++j) {
                int col = j * 16 + l15;
                int br = col >> 5, m = col & 31;
                u16x4 pk;
#pragma unroll
                for (int g = 0; g < 4; ++g) pk[g] = f2bf(c1[i][j][g]);
                *(u16x4*)(bt + (r * 32 + m) * 72 + br * 32 + q0) = pk;
            }
        }
    }
    __syncthreads();

    // ---- step2 MFMA: D2[l][(r,m)] ----
    f32x4 c2[2][2] = {};
#pragma unroll
    for (int ks = 0; ks < 2; ++ks) {
        bf16x8 af2[2], bf2[2];
#pragma unroll
        for (int i = 0; i < 2; ++i)
            af2[i] = *(const bf16x8*)(a2 + (i * 16 + l15) * 72 + ks * 32 + quad * 8);
#pragma unroll
        for (int j = 0; j < 2; ++j) {
            int col = (wave * 2 + j) * 16 + l15;
            bf2[j] = *(const bf16x8*)(bt + col * 72 + ks * 32 + quad * 8);
        }
#pragma unroll
        for (int i = 0; i < 2; ++i)
#pragma unroll
            for (int j = 0; j < 2; ++j)
                c2[i][j] = __builtin_amdgcn_mfma_f32_16x16x32_bf16(af2[i], bf2[j], c2[i][j], 0, 0, 0);
    }
    // epilogue: out[bs0+r, l*32+m] = D2 + bias  (coalesced in m)
#pragma unroll
    for (int i = 0; i < 2; ++i) {
#pragma unroll
        for (int j = 0; j < 2; ++j) {
            int col = (wave * 2 + j) * 16 + l15;
            int r = col >> 5, m = col & 31;
            float* orow = out + (size_t)(bs0 + r) * 768;
#pragma unroll
            for (int g = 0; g < 4; ++g) {
                int l = i * 16 + quad * 4 + g;
                if (l < 24) orow[l * 32 + m] = c2[i][j][g] + bias_s[l * 32 + m];
            }
        }
    }
}

// ---------- gemm: out += xb @ WeffB^T : shared-weight MFMA GEMM, RMW epilogue ----------
__global__ __launch_bounds__(256, 2) void gemm_add_kernel(
    const unsigned short* __restrict__ Xb, const unsigned short* __restrict__ WeffB,
    float* __restrict__ out) {
    __shared__ __align__(16) unsigned short As[128 * 64];
    __shared__ __align__(16) unsigned short Bs[128 * 64];
    const int tid = threadIdx.x;
    const int wave = tid >> 6, lane = tid & 63;
    const int b = blockIdx.z, mt = blockIdx.y, nt = blockIdx.x;
    const int s0 = mt * 128, n0 = nt * 128;
    const unsigned short* Ab = Xb + (size_t)(b * 256 + s0) * 768;
    const unsigned short* Bb = WeffB + (size_t)n0 * 768;
    const int wm = wave & 1, wn = wave >> 1;

    f32x4 acc[4][4] = {};

    const int lrow = lane >> 3;
    const int lcp = lane & 7;

    for (int kk = 0; kk < 768; kk += 64) {
#pragma unroll
        for (int u = 0; u < 4; ++u) {
            int tA = wave * 4 + u;
            int r = tA * 8 + lrow;
            int c = lcp ^ (r & 7);
            load_lds_16(Ab + (size_t)r * 768 + kk + c * 8, (void*)(As + tA * 512));
            load_lds_16(Bb + (size_t)r * 768 + kk + c * 8, (void*)(Bs + tA * 512));
        }
        __syncthreads();
#pragma unroll
        for (int h = 0; h < 2; ++h) {
            const int cb = h * 4 + (lane >> 4);
            const int rl = lane & 15;
            bf16x8 af[4], bfr[4];
#pragma unroll
            for (int i = 0; i < 4; ++i) {
                int r = wm * 64 + i * 16 + rl;
                int c = cb ^ (r & 7);
                af[i] = *(const bf16x8*)(As + r * 64 + c * 8);
            }
#pragma unroll
            for (int j = 0; j < 4; ++j) {
                int r = wn * 64 + j * 16 + rl;
                int c = cb ^ (r & 7);
                bfr[j] = *(const bf16x8*)(Bs + r * 64 + c * 8);
            }
#pragma unroll
            for (int i = 0; i < 4; ++i)
#pragma unroll
                for (int j = 0; j < 4; ++j)
                    acc[i][j] = __builtin_amdgcn_mfma_f32_16x16x32_bf16(af[i], bfr[j], acc[i][j], 0, 0, 0);
        }
        __syncthreads();
    }

    const int cl = lane & 15, rq = lane >> 4;
#pragma unroll
    for (int j = 0; j < 4; ++j) {
        int n = n0 + wn * 64 + j * 16 + cl;
#pragma unroll
        for (int i = 0; i < 4; ++i) {
            int mrow = s0 + wm * 64 + i * 16 + rq * 4;
            float* op = out + (size_t)(b * 256 + mrow) * 768 + n;
#pragma unroll
            for (int g = 0; g < 4; ++g) op[(size_t)g * 768] += acc[i][j][g];
        }
    }
}

// ---------- fallback path (small ws) ----------
__global__ void weff_kernel(const float* __restrict__ W, const float* __restrict__ A,
                            const float* __restrict__ B, float* __restrict__ Weff) {
    int o = blockIdx.x / 3;
    int k = (blockIdx.x % 3) * 256 + threadIdx.x;
    float acc = W[o * 768 + k];
#pragma unroll
    for (int r = 0; r < 8; ++r) acc += 2.0f * B[o * 8 + r] * A[r * 768 + k];
    Weff[o * 768 + k] = acc;
}

__global__ void wq2_kernel(const float* __restrict__ uh, const float* __restrict__ ih,
                           const float* __restrict__ Wu, const float* __restrict__ Wi,
                           float* __restrict__ wqu, float* __restrict__ wqi) {
    int bx = blockIdx.x;
    int og = bx % 192;
    int rest = bx / 192;
    int b = rest & 63;
    int br = rest >> 6;
    int wave = threadIdx.x >> 6, lane = threadIdx.x & 63;
    int o = og * 4 + wave;
    const float* h = (br ? ih : uh) + b * 768;
    const float* Wrow = (br ? Wi : Wu) + (size_t)o * 768;
    const float4* hp = (const float4*)(h + lane * 12);
    const float4* wp = (const float4*)(Wrow + lane * 12);
    float s = 0.0f;
#pragma unroll
    for (int j = 0; j < 3; ++j) {
        float4 hv = hp[j], wv = wp[j];
        s += hv.x * wv.x + hv.y * wv.y + hv.z * wv.z + hv.w * wv.w;
    }
#pragma unroll
    for (int off = 32; off; off >>= 1) s += __shfl_down(s, off);
    if (lane == 0) (br ? wqi : wqu)[b * 768 + o] = s;
}

__global__ void naive_kernel(const float* __restrict__ x, const float* __restrict__ Weff,
                             const float* __restrict__ wqu, const float* __restrict__ wqi,
                             const float* __restrict__ VU, const float* __restrict__ VI,
                             const float* __restrict__ bias, float* __restrict__ out) {
    int bs_ = blockIdx.x / 3;
    int chunk = blockIdx.x % 3;
    int b = bs_ >> 8;
    __shared__ float xs[768];
    for (int i = threadIdx.x; i < 768; i += 256) xs[i] = x[(size_t)bs_ * 768 + i];
    __syncthreads();
    int o = chunk * 256 + threadIdx.x;
    int m = o & 31, l = o >> 5;
    float acc = bias[o];
    for (int q = 0; q < 32; ++q) {
        float wu = wqu[b * 768 + q * 24 + l];
        float wi = wqi[b * 768 + q * 24 + l];
#pragma unroll
        for (int n = 0; n < 24; ++n) {
            int k = q * 24 + n;
            float w = Weff[o * 768 + k] + VU[n * 32 + m] * wu + VI[n * 32 + m] * wi;
            acc += xs[k] * w;
        }
    }
    out[(size_t)bs_ * 768 + o] = acc;
}

extern "C" void kernel_launch(void* const* d_in, const int* in_sizes, int n_in,
                              void* d_out, int out_size, void* d_ws, size_t ws_size,
                              hipStream_t stream) {
    const float* x  = (const float*)d_in[0];
    const float* uh = (const float*)d_in[1];
    const float* ih = (const float*)d_in[2];
    const float* W  = (const float*)d_in[3];
    const float* bv = (const float*)d_in[4];
    const float* A  = (const float*)d_in[5];
    const float* B  = (const float*)d_in[6];
    const float* Wu = (const float*)d_in[7];
    const float* VU = (const float*)d_in[8];
    const float* Wi = (const float*)d_in[9];
    const float* VI = (const float*)d_in[10];
    float* out = (float*)d_out;

    const size_t off_xb   = 0;                        // 25,165,824 B
    const size_t off_weff = 25165824;                 // 1,179,648 B (bf16)
    const size_t off_wqu  = off_weff + 1179648;       // 196,608 B
    const size_t off_wqi  = off_wqu + 196608;
    const size_t need     = off_wqi + 196608;         // ~26.7 MB

    char* ws = (char*)d_ws;
    if (ws_size >= need) {
        unsigned short* xb    = (unsigned short*)(ws + off_xb);
        unsigned short* weffB = (unsigned short*)(ws + off_weff);
        float* wqu = (float*)(ws + off_wqu);
        float* wqi = (float*)(ws + off_wqi);
        prep_kernel<<<33024, 256, 0, stream>>>(x, xb, W, A, B, weffB, uh, ih, Wu, Wi, wqu, wqi);
        kron_kernel<<<4096, 256, 0, stream>>>(xb, VU, VI, wqu, wqi, bv, out);
        gemm_add_kernel<<<dim3(6, 2, 64), 256, 0, stream>>>(xb, weffB, out);
    } else {
        float* weff = (float*)ws;
        float* wqu  = weff + 589824;
        float* wqi  = wqu + 49152;
        weff_kernel<<<2304, 256, 0, stream>>>(W, A, B, weff);
        wq2_kernel<<<24576, 256, 0, stream>>>(uh, ih, Wu, Wi, wqu, wqi);
        naive_kernel<<<49152, 256, 0, stream>>>(x, weff, wqu, wqi, VU, VI, bv, out);
    }
}

// Round 4
// 183.572 us; speedup vs baseline: 1.4780x; 1.1468x over previous
//
#include <hip/hip_runtime.h>
#include <hip/hip_bf16.h>

typedef __bf16 bf16x8 __attribute__((ext_vector_type(8)));
typedef float f32x4 __attribute__((ext_vector_type(4)));
typedef unsigned short u16x8 __attribute__((ext_vector_type(8)));

__device__ __forceinline__ unsigned short f2bf(float f) {
    unsigned int u = __builtin_bit_cast(unsigned int, f);
    unsigned int r = (u + 0x7FFFu + ((u >> 16) & 1u)) >> 16;
    return (unsigned short)r;
}

__device__ __forceinline__ void load_lds_16(const void* g, void* lds) {
    __builtin_amdgcn_global_load_lds(
        (const __attribute__((address_space(1))) unsigned int*)g,
        (__attribute__((address_space(3))) unsigned int*)lds, 16, 0, 0);
}

// ---------- prep: fused conv_x (bx<6144) + weffB (bx<8448) + wq (rest) ----------
__global__ void prep_kernel(const float* __restrict__ x, unsigned short* __restrict__ xb,
                            const float* __restrict__ W, const float* __restrict__ A,
                            const float* __restrict__ B, unsigned short* __restrict__ weffB,
                            const float* __restrict__ uh, const float* __restrict__ ih,
                            const float* __restrict__ Wu, const float* __restrict__ Wi,
                            float* __restrict__ wqu, float* __restrict__ wqi) {
    int bx = blockIdx.x;
    int t = threadIdx.x;
    if (bx < 6144) {
        int i = bx * 256 + t;
        const float4* xp = (const float4*)x;
        float4 a = xp[i * 2];
        float4 c = xp[i * 2 + 1];
        u16x8 r;
        r[0] = f2bf(a.x); r[1] = f2bf(a.y); r[2] = f2bf(a.z); r[3] = f2bf(a.w);
        r[4] = f2bf(c.x); r[5] = f2bf(c.y); r[6] = f2bf(c.z); r[7] = f2bf(c.w);
        *(u16x8*)(xb + (size_t)i * 8) = r;
    } else if (bx < 8448) {
        int idx = bx - 6144;
        int o = idx / 3;
        int k = (idx % 3) * 256 + t;
        float acc = W[o * 768 + k];
#pragma unroll
        for (int r = 0; r < 8; ++r) acc += 2.0f * B[o * 8 + r] * A[r * 768 + k];
        weffB[o * 768 + k] = f2bf(acc);
    } else {
        int b2 = bx - 8448;                 // og(192) fastest -> same-og blocks same XCD
        int og = b2 % 192;
        int rest = b2 / 192;
        int b = rest & 63;
        int br = rest >> 6;
        int wave = t >> 6, lane = t & 63;
        int o = og * 4 + wave;
        const float* h = (br ? ih : uh) + b * 768;
        const float* Wrow = (br ? Wi : Wu) + (size_t)o * 768;
        const float4* hp = (const float4*)(h + lane * 12);
        const float4* wp = (const float4*)(Wrow + lane * 12);
        float s = 0.0f;
#pragma unroll
        for (int j = 0; j < 3; ++j) {
            float4 hv = hp[j], wv = wp[j];
            s += hv.x * wv.x + hv.y * wv.y + hv.z * wv.z + hv.w * wv.w;
        }
#pragma unroll
        for (int off = 32; off; off >>= 1) s += __shfl_down(s, off);
        if (lane == 0) (br ? wqi : wqu)[b * 768 + o] = s;
    }
}

// ---------- fused GEMM: out[b,s,o] = bias[o] + sum_k x[s,k]*(Weff[o,k] + K_b[k,o]) ----------
// K_b[k,o] = VU[n,m]*wqu[b,q,l] + VI[n,m]*wqi[b,q,l];  k=q*24+n, o=l*32+m.
// Per k-iter, the 64x128 K tile (Ks) is built by VALU during async staging of As/Bs,
// then each fragment issues two MFMAs: acc += A*Bw; acc += A*Bk.
__global__ __launch_bounds__(256, 2) void gemm_fused_kernel(
    const unsigned short* __restrict__ Xb, const unsigned short* __restrict__ WeffB,
    const float* __restrict__ VU, const float* __restrict__ VI,
    const float* __restrict__ wqu, const float* __restrict__ wqi,
    const float* __restrict__ bias, float* __restrict__ out) {
    __shared__ __align__(16) unsigned short As[128 * 64];
    __shared__ __align__(16) unsigned short Bs[128 * 64];
    __shared__ __align__(16) unsigned short Ks[128 * 64];
    __shared__ __align__(16) float vui[32 * 26 * 2];   // [m][n pad26][{u,i}]
    __shared__ float wqs[4 * 32 * 2];                  // [lr][q][{u,i}]
    __shared__ float bias_s[128];
    const int tid = threadIdx.x;
    const int wave = tid >> 6, lane = tid & 63;
    const int id = blockIdx.x;            // nt*128 + b*2 + mt  (same-A blocks = same XCD)
    const int nt = id >> 7, rem = id & 127, b = rem >> 1, mt = rem & 1;
    const int s0 = mt * 128, n0 = nt * 128;

    // ---- one-time staging ----
    for (int i = tid; i < 768; i += 256) {
        int n = i >> 5, m = i & 31;
        vui[(m * 26 + n) * 2] = VU[i];
        vui[(m * 26 + n) * 2 + 1] = VI[i];
    }
    if (tid < 128) {
        int q = tid >> 2, lr = tid & 3;
        int l = nt * 4 + lr;
        wqs[(lr * 32 + q) * 2] = wqu[b * 768 + q * 24 + l];
        wqs[(lr * 32 + q) * 2 + 1] = wqi[b * 768 + q * 24 + l];
        bias_s[tid] = bias[n0 + tid];
    }
    __syncthreads();

    const unsigned short* Abase = Xb + (size_t)(b * 256 + s0) * 768;
    const unsigned short* Bbase = WeffB + (size_t)n0 * 768;
    const int wm = wave & 1, wn = wave >> 1;
    const int lrow = lane >> 3, lcp = lane & 7;

    f32x4 acc[4][4] = {};

    for (int kk = 0; kk < 768; kk += 64) {
#pragma unroll
        for (int u = 0; u < 4; ++u) {
            int tA = wave * 4 + u;
            int r = tA * 8 + lrow;                // 0..127 local row
            int c = lcp ^ (r & 7);                // logical 16B chunk into slot lcp
            load_lds_16(Abase + (size_t)r * 768 + kk + c * 8, (void*)(As + tA * 512));
            load_lds_16(Bbase + (size_t)r * 768 + kk + c * 8, (void*)(Bs + tA * 512));
            // build Ks chunk: k = kb..kb+7, constant q, n = n0c..n0c+7 (no wrap)
            int kb = kk + c * 8;
            int q = (kb * 2731) >> 16;
            int n0c = kb - q * 24;                // 0, 8, or 16
            int m = r & 31, lr = r >> 5;
            const float* vp = &vui[(m * 26 + n0c) * 2];
            float wu = wqs[(lr * 32 + q) * 2];
            float wi = wqs[(lr * 32 + q) * 2 + 1];
            u16x8 kv;
#pragma unroll
            for (int j = 0; j < 8; ++j)
                kv[j] = f2bf(vp[j * 2] * wu + vp[j * 2 + 1] * wi);
            *(u16x8*)(Ks + r * 64 + lcp * 8) = kv;
        }
        __syncthreads();
#pragma unroll
        for (int h = 0; h < 2; ++h) {
            const int cb = h * 4 + (lane >> 4);
            const int rl = lane & 15;
            bf16x8 af[4], bw[4], bk[4];
#pragma unroll
            for (int i = 0; i < 4; ++i) {
                int r = wm * 64 + i * 16 + rl;
                int c = cb ^ (r & 7);
                af[i] = *(const bf16x8*)(As + r * 64 + c * 8);
            }
#pragma unroll
            for (int j = 0; j < 4; ++j) {
                int r = wn * 64 + j * 16 + rl;
                int c = cb ^ (r & 7);
                bw[j] = *(const bf16x8*)(Bs + r * 64 + c * 8);
                bk[j] = *(const bf16x8*)(Ks + r * 64 + c * 8);
            }
#pragma unroll
            for (int i = 0; i < 4; ++i)
#pragma unroll
                for (int j = 0; j < 4; ++j) {
                    acc[i][j] = __builtin_amdgcn_mfma_f32_16x16x32_bf16(af[i], bw[j], acc[i][j], 0, 0, 0);
                    acc[i][j] = __builtin_amdgcn_mfma_f32_16x16x32_bf16(af[i], bk[j], acc[i][j], 0, 0, 0);
                }
        }
        __syncthreads();
    }

    // epilogue: C/D layout col=lane&15, row=(lane>>4)*4+reg
    const int cl = lane & 15, rq = lane >> 4;
#pragma unroll
    for (int j = 0; j < 4; ++j) {
        int nn = wn * 64 + j * 16 + cl;           // local col 0..127
        float bv = bias_s[nn];
#pragma unroll
        for (int i = 0; i < 4; ++i) {
            int mrow = s0 + wm * 64 + i * 16 + rq * 4;
            float* op = out + (size_t)(b * 256 + mrow) * 768 + n0 + nn;
#pragma unroll
            for (int g = 0; g < 4; ++g) op[(size_t)g * 768] = acc[i][j][g] + bv;
        }
    }
}

// ---------- fallback path (small ws) ----------
__global__ void weff_kernel(const float* __restrict__ W, const float* __restrict__ A,
                            const float* __restrict__ B, float* __restrict__ Weff) {
    int o = blockIdx.x / 3;
    int k = (blockIdx.x % 3) * 256 + threadIdx.x;
    float acc = W[o * 768 + k];
#pragma unroll
    for (int r = 0; r < 8; ++r) acc += 2.0f * B[o * 8 + r] * A[r * 768 + k];
    Weff[o * 768 + k] = acc;
}

__global__ void wq2_kernel(const float* __restrict__ uh, const float* __restrict__ ih,
                           const float* __restrict__ Wu, const float* __restrict__ Wi,
                           float* __restrict__ wqu, float* __restrict__ wqi) {
    int bx = blockIdx.x;
    int og = bx % 192;
    int rest = bx / 192;
    int b = rest & 63;
    int br = rest >> 6;
    int wave = threadIdx.x >> 6, lane = threadIdx.x & 63;
    int o = og * 4 + wave;
    const float* h = (br ? ih : uh) + b * 768;
    const float* Wrow = (br ? Wi : Wu) + (size_t)o * 768;
    const float4* hp = (const float4*)(h + lane * 12);
    const float4* wp = (const float4*)(Wrow + lane * 12);
    float s = 0.0f;
#pragma unroll
    for (int j = 0; j < 3; ++j) {
        float4 hv = hp[j], wv = wp[j];
        s += hv.x * wv.x + hv.y * wv.y + hv.z * wv.z + hv.w * wv.w;
    }
#pragma unroll
    for (int off = 32; off; off >>= 1) s += __shfl_down(s, off);
    if (lane == 0) (br ? wqi : wqu)[b * 768 + o] = s;
}

__global__ void naive_kernel(const float* __restrict__ x, const float* __restrict__ Weff,
                             const float* __restrict__ wqu, const float* __restrict__ wqi,
                             const float* __restrict__ VU, const float* __restrict__ VI,
                             const float* __restrict__ bias, float* __restrict__ out) {
    int bs_ = blockIdx.x / 3;
    int chunk = blockIdx.x % 3;
    int b = bs_ >> 8;
    __shared__ float xs[768];
    for (int i = threadIdx.x; i < 768; i += 256) xs[i] = x[(size_t)bs_ * 768 + i];
    __syncthreads();
    int o = chunk * 256 + threadIdx.x;
    int m = o & 31, l = o >> 5;
    float acc = bias[o];
    for (int q = 0; q < 32; ++q) {
        float wu = wqu[b * 768 + q * 24 + l];
        float wi = wqi[b * 768 + q * 24 + l];
#pragma unroll
        for (int n = 0; n < 24; ++n) {
            int k = q * 24 + n;
            float w = Weff[o * 768 + k] + VU[n * 32 + m] * wu + VI[n * 32 + m] * wi;
            acc += xs[k] * w;
        }
    }
    out[(size_t)bs_ * 768 + o] = acc;
}

extern "C" void kernel_launch(void* const* d_in, const int* in_sizes, int n_in,
                              void* d_out, int out_size, void* d_ws, size_t ws_size,
                              hipStream_t stream) {
    const float* x  = (const float*)d_in[0];
    const float* uh = (const float*)d_in[1];
    const float* ih = (const float*)d_in[2];
    const float* W  = (const float*)d_in[3];
    const float* bv = (const float*)d_in[4];
    const float* A  = (const float*)d_in[5];
    const float* B  = (const float*)d_in[6];
    const float* Wu = (const float*)d_in[7];
    const float* VU = (const float*)d_in[8];
    const float* Wi = (const float*)d_in[9];
    const float* VI = (const float*)d_in[10];
    float* out = (float*)d_out;

    const size_t off_xb   = 0;                        // 25,165,824 B
    const size_t off_weff = 25165824;                 // 1,179,648 B (bf16)
    const size_t off_wqu  = off_weff + 1179648;       // 196,608 B
    const size_t off_wqi  = off_wqu + 196608;
    const size_t need     = off_wqi + 196608;         // ~26.7 MB

    char* ws = (char*)d_ws;
    if (ws_size >= need) {
        unsigned short* xb    = (unsigned short*)(ws + off_xb);
        unsigned short* weffB = (unsigned short*)(ws + off_weff);
        float* wqu = (float*)(ws + off_wqu);
        float* wqi = (float*)(ws + off_wqi);
        prep_kernel<<<33024, 256, 0, stream>>>(x, xb, W, A, B, weffB, uh, ih, Wu, Wi, wqu, wqi);
        gemm_fused_kernel<<<768, 256, 0, stream>>>(xb, weffB, VU, VI, wqu, wqi, bv, out);
    } else {
        float* weff = (float*)ws;
        float* wqu  = weff + 589824;
        float* wqi  = wqu + 49152;
        weff_kernel<<<2304, 256, 0, stream>>>(W, A, B, weff);
        wq2_kernel<<<24576, 256, 0, stream>>>(uh, ih, Wu, Wi, wqu, wqi);
        naive_kernel<<<49152, 256, 0, stream>>>(x, weff, wqu, wqi, VU, VI, bv, out);
    }
}

// Round 5
// 177.140 us; speedup vs baseline: 1.5316x; 1.0363x over previous
//
#include <hip/hip_runtime.h>
#include <hip/hip_bf16.h>

typedef __bf16 bf16x8 __attribute__((ext_vector_type(8)));
typedef float f32x4 __attribute__((ext_vector_type(4)));
typedef unsigned short u16x8 __attribute__((ext_vector_type(8)));

__device__ __forceinline__ unsigned short f2bf(float f) {
    unsigned int u = __builtin_bit_cast(unsigned int, f);
    unsigned int r = (u + 0x7FFFu + ((u >> 16) & 1u)) >> 16;
    return (unsigned short)r;
}

__device__ __forceinline__ void load_lds_16(const void* g, void* lds) {
    __builtin_amdgcn_global_load_lds(
        (const __attribute__((address_space(1))) unsigned int*)g,
        (__attribute__((address_space(3))) unsigned int*)lds, 16, 0, 0);
}

// ---------- prep: fused conv_x (bx<6144) + weffB (bx<8448) + wq (rest) ----------
__global__ void prep_kernel(const float* __restrict__ x, unsigned short* __restrict__ xb,
                            const float* __restrict__ W, const float* __restrict__ A,
                            const float* __restrict__ B, unsigned short* __restrict__ weffB,
                            const float* __restrict__ uh, const float* __restrict__ ih,
                            const float* __restrict__ Wu, const float* __restrict__ Wi,
                            float* __restrict__ wqu, float* __restrict__ wqi) {
    int bx = blockIdx.x;
    int t = threadIdx.x;
    if (bx < 6144) {
        int i = bx * 256 + t;
        const float4* xp = (const float4*)x;
        float4 a = xp[i * 2];
        float4 c = xp[i * 2 + 1];
        u16x8 r;
        r[0] = f2bf(a.x); r[1] = f2bf(a.y); r[2] = f2bf(a.z); r[3] = f2bf(a.w);
        r[4] = f2bf(c.x); r[5] = f2bf(c.y); r[6] = f2bf(c.z); r[7] = f2bf(c.w);
        *(u16x8*)(xb + (size_t)i * 8) = r;
    } else if (bx < 8448) {
        int idx = bx - 6144;
        int o = idx / 3;
        int k = (idx % 3) * 256 + t;
        float acc = W[o * 768 + k];
#pragma unroll
        for (int r = 0; r < 8; ++r) acc += 2.0f * B[o * 8 + r] * A[r * 768 + k];
        weffB[o * 768 + k] = f2bf(acc);
    } else {
        int b2 = bx - 8448;
        int og = b2 % 192;
        int rest = b2 / 192;
        int b = rest & 63;
        int br = rest >> 6;
        int wave = t >> 6, lane = t & 63;
        int o = og * 4 + wave;
        const float* h = (br ? ih : uh) + b * 768;
        const float* Wrow = (br ? Wi : Wu) + (size_t)o * 768;
        const float4* hp = (const float4*)(h + lane * 12);
        const float4* wp = (const float4*)(Wrow + lane * 12);
        float s = 0.0f;
#pragma unroll
        for (int j = 0; j < 3; ++j) {
            float4 hv = hp[j], wv = wp[j];
            s += hv.x * wv.x + hv.y * wv.y + hv.z * wv.z + hv.w * wv.w;
        }
#pragma unroll
        for (int off = 32; off; off >>= 1) s += __shfl_down(s, off);
        if (lane == 0) (br ? wqi : wqu)[b * 768 + o] = s;
    }
}

// ---------- fused GEMM: out[b,s,o] = bias[o] + sum_k x[s,k]*(Weff[o,k] + K_b[k,o]) ----------
// K_b[k,o] = VU[n,m]*wqu[b,q,l] + VI[n,m]*wqi[b,q,l];  k=q*24+n, o=l*32+m.
// Ks (64x128) built per k-iter by VALU from packed-bf16 V table + wq LDS, while
// global_load_lds streams As/Bs. Two MFMAs per fragment: acc += A*Bw + A*Bk.
__global__ __launch_bounds__(256, 3) void gemm_fused_kernel(
    const unsigned short* __restrict__ Xb, const unsigned short* __restrict__ WeffB,
    const float* __restrict__ VU, const float* __restrict__ VI,
    const float* __restrict__ wqu, const float* __restrict__ wqi,
    const float* __restrict__ bias, float* __restrict__ out) {
    __shared__ __align__(16) unsigned short As[128 * 64];
    __shared__ __align__(16) unsigned short Bs[128 * 64];
    __shared__ __align__(16) unsigned short Ks[128 * 64];
    __shared__ __align__(16) unsigned int vui[32 * 26]; // [m][n pad26], (bf16(VU)<<16)|bf16(VI)
    __shared__ __align__(16) float wqs[32 * 8];          // [q][lr][{u,i}]
    __shared__ float bias_s[128];
    const int tid = threadIdx.x;
    const int wave = tid >> 6, lane = tid & 63;
    const int id = blockIdx.x;            // nt*128 + b*2 + mt (same-A blocks = same XCD)
    const int nt = id >> 7, rem = id & 127, b = rem >> 1, mt = rem & 1;
    const int s0 = mt * 128, n0 = nt * 128;

    // ---- one-time staging ----
    for (int i = tid; i < 768; i += 256) {
        int n = i >> 5, m = i & 31;
        vui[m * 26 + n] = ((unsigned int)f2bf(VU[i]) << 16) | (unsigned int)f2bf(VI[i]);
    }
    {
        int q = tid >> 3, lr = (tid >> 1) & 3, br = tid & 1;
        const float* wq = br ? wqi : wqu;
        wqs[tid] = wq[b * 768 + q * 24 + nt * 4 + lr];
    }
    if (tid < 128) bias_s[tid] = bias[n0 + tid];
    __syncthreads();

    const unsigned short* Abase = Xb + (size_t)(b * 256 + s0) * 768;
    const unsigned short* Bbase = WeffB + (size_t)n0 * 768;
    const int wm = wave & 1, wn = wave >> 1;
    const int lrow = lane >> 3, lcp = lane & 7;      // DMA mapping
    const int mp = tid & 31, cp = tid >> 5;          // Ks-build mapping
    const int psl = cp ^ (mp & 7);                   // physical chunk slot (all 4 rows)

    f32x4 acc[4][4] = {};

    for (int kk = 0; kk < 768; kk += 64) {
        // async DMA staging of As/Bs
#pragma unroll
        for (int u = 0; u < 4; ++u) {
            int tA = wave * 4 + u;
            int r = tA * 8 + lrow;
            int c = lcp ^ (r & 7);
            load_lds_16(Abase + (size_t)r * 768 + kk + c * 8, (void*)(As + tA * 512));
            load_lds_16(Bbase + (size_t)r * 768 + kk + c * 8, (void*)(Bs + tA * 512));
        }
        // Ks build: logical chunk cp, rows lr*32+mp; k = kb..kb+7, const q, no n-wrap
        {
            int kb = kk + cp * 8;
            int q = (kb * 2731) >> 16;
            int n0c = kb - q * 24;                   // 0, 8, or 16
            const unsigned int* vp = &vui[mp * 26 + n0c];
            uint2 pv01 = *(const uint2*)(vp);
            uint2 pv23 = *(const uint2*)(vp + 2);
            uint2 pv45 = *(const uint2*)(vp + 4);
            uint2 pv67 = *(const uint2*)(vp + 6);
            unsigned int pv[8] = {pv01.x, pv01.y, pv23.x, pv23.y, pv45.x, pv45.y, pv67.x, pv67.y};
            float fu[8], fi[8];
#pragma unroll
            for (int j = 0; j < 8; ++j) {
                fu[j] = __builtin_bit_cast(float, pv[j] & 0xFFFF0000u);
                fi[j] = __builtin_bit_cast(float, pv[j] << 16);
            }
            const float2* wp = (const float2*)&wqs[q * 8];
#pragma unroll
            for (int lr = 0; lr < 4; ++lr) {
                float2 w = wp[lr];
                u16x8 kv;
#pragma unroll
                for (int j = 0; j < 8; ++j) {
                    float v = fu[j] * w.x + fi[j] * w.y;
                    kv[j] = (unsigned short)(__builtin_bit_cast(unsigned int, v) >> 16);
                }
                *(u16x8*)(Ks + (lr * 32 + mp) * 64 + psl * 8) = kv;
            }
        }
        __syncthreads();
#pragma unroll
        for (int h = 0; h < 2; ++h) {
            const int cb = h * 4 + (lane >> 4);
            const int rl = lane & 15;
            bf16x8 af[4], bw[4], bk[4];
#pragma unroll
            for (int i = 0; i < 4; ++i) {
                int r = wm * 64 + i * 16 + rl;
                int c = cb ^ (r & 7);
                af[i] = *(const bf16x8*)(As + r * 64 + c * 8);
            }
#pragma unroll
            for (int j = 0; j < 4; ++j) {
                int r = wn * 64 + j * 16 + rl;
                int c = cb ^ (r & 7);
                bw[j] = *(const bf16x8*)(Bs + r * 64 + c * 8);
                bk[j] = *(const bf16x8*)(Ks + r * 64 + c * 8);
            }
#pragma unroll
            for (int i = 0; i < 4; ++i)
#pragma unroll
                for (int j = 0; j < 4; ++j) {
                    acc[i][j] = __builtin_amdgcn_mfma_f32_16x16x32_bf16(af[i], bw[j], acc[i][j], 0, 0, 0);
                    acc[i][j] = __builtin_amdgcn_mfma_f32_16x16x32_bf16(af[i], bk[j], acc[i][j], 0, 0, 0);
                }
        }
        __syncthreads();
    }

    // epilogue: C/D layout col=lane&15, row=(lane>>4)*4+reg
    const int cl = lane & 15, rq = lane >> 4;
#pragma unroll
    for (int j = 0; j < 4; ++j) {
        int nn = wn * 64 + j * 16 + cl;
        float bv = bias_s[nn];
#pragma unroll
        for (int i = 0; i < 4; ++i) {
            int mrow = s0 + wm * 64 + i * 16 + rq * 4;
            float* op = out + (size_t)(b * 256 + mrow) * 768 + n0 + nn;
#pragma unroll
            for (int g = 0; g < 4; ++g) op[(size_t)g * 768] = acc[i][j][g] + bv;
        }
    }
}

// ---------- fallback path (small ws) ----------
__global__ void weff_kernel(const float* __restrict__ W, const float* __restrict__ A,
                            const float* __restrict__ B, float* __restrict__ Weff) {
    int o = blockIdx.x / 3;
    int k = (blockIdx.x % 3) * 256 + threadIdx.x;
    float acc = W[o * 768 + k];
#pragma unroll
    for (int r = 0; r < 8; ++r) acc += 2.0f * B[o * 8 + r] * A[r * 768 + k];
    Weff[o * 768 + k] = acc;
}

__global__ void wq2_kernel(const float* __restrict__ uh, const float* __restrict__ ih,
                           const float* __restrict__ Wu, const float* __restrict__ Wi,
                           float* __restrict__ wqu, float* __restrict__ wqi) {
    int bx = blockIdx.x;
    int og = bx % 192;
    int rest = bx / 192;
    int b = rest & 63;
    int br = rest >> 6;
    int wave = threadIdx.x >> 6, lane = threadIdx.x & 63;
    int o = og * 4 + wave;
    const float* h = (br ? ih : uh) + b * 768;
    const float* Wrow = (br ? Wi : Wu) + (size_t)o * 768;
    const float4* hp = (const float4*)(h + lane * 12);
    const float4* wp = (const float4*)(Wrow + lane * 12);
    float s = 0.0f;
#pragma unroll
    for (int j = 0; j < 3; ++j) {
        float4 hv = hp[j], wv = wp[j];
        s += hv.x * wv.x + hv.y * wv.y + hv.z * wv.z + hv.w * wv.w;
    }
#pragma unroll
    for (int off = 32; off; off >>= 1) s += __shfl_down(s, off);
    if (lane == 0) (br ? wqi : wqu)[b * 768 + o] = s;
}

__global__ void naive_kernel(const float* __restrict__ x, const float* __restrict__ Weff,
                             const float* __restrict__ wqu, const float* __restrict__ wqi,
                             const float* __restrict__ VU, const float* __restrict__ VI,
                             const float* __restrict__ bias, float* __restrict__ out) {
    int bs_ = blockIdx.x / 3;
    int chunk = blockIdx.x % 3;
    int b = bs_ >> 8;
    __shared__ float xs[768];
    for (int i = threadIdx.x; i < 768; i += 256) xs[i] = x[(size_t)bs_ * 768 + i];
    __syncthreads();
    int o = chunk * 256 + threadIdx.x;
    int m = o & 31, l = o >> 5;
    float acc = bias[o];
    for (int q = 0; q < 32; ++q) {
        float wu = wqu[b * 768 + q * 24 + l];
        float wi = wqi[b * 768 + q * 24 + l];
#pragma unroll
        for (int n = 0; n < 24; ++n) {
            int k = q * 24 + n;
            float w = Weff[o * 768 + k] + VU[n * 32 + m] * wu + VI[n * 32 + m] * wi;
            acc += xs[k] * w;
        }
    }
    out[(size_t)bs_ * 768 + o] = acc;
}

extern "C" void kernel_launch(void* const* d_in, const int* in_sizes, int n_in,
                              void* d_out, int out_size, void* d_ws, size_t ws_size,
                              hipStream_t stream) {
    const float* x  = (const float*)d_in[0];
    const float* uh = (const float*)d_in[1];
    const float* ih = (const float*)d_in[2];
    const float* W  = (const float*)d_in[3];
    const float* bv = (const float*)d_in[4];
    const float* A  = (const float*)d_in[5];
    const float* B  = (const float*)d_in[6];
    const float* Wu = (const float*)d_in[7];
    const float* VU = (const float*)d_in[8];
    const float* Wi = (const float*)d_in[9];
    const float* VI = (const float*)d_in[10];
    float* out = (float*)d_out;

    const size_t off_xb   = 0;                        // 25,165,824 B
    const size_t off_weff = 25165824;                 // 1,179,648 B (bf16)
    const size_t off_wqu  = off_weff + 1179648;       // 196,608 B
    const size_t off_wqi  = off_wqu + 196608;
    const size_t need     = off_wqi + 196608;         // ~26.7 MB

    char* ws = (char*)d_ws;
    if (ws_size >= need) {
        unsigned short* xb    = (unsigned short*)(ws + off_xb);
        unsigned short* weffB = (unsigned short*)(ws + off_weff);
        float* wqu = (float*)(ws + off_wqu);
        float* wqi = (float*)(ws + off_wqi);
        prep_kernel<<<33024, 256, 0, stream>>>(x, xb, W, A, B, weffB, uh, ih, Wu, Wi, wqu, wqi);
        gemm_fused_kernel<<<768, 256, 0, stream>>>(xb, weffB, VU, VI, wqu, wqi, bv, out);
    } else {
        float* weff = (float*)ws;
        float* wqu  = weff + 589824;
        float* wqi  = wqu + 49152;
        weff_kernel<<<2304, 256, 0, stream>>>(W, A, B, weff);
        wq2_kernel<<<24576, 256, 0, stream>>>(uh, ih, Wu, Wi, wqu, wqi);
        naive_kernel<<<49152, 256, 0, stream>>>(x, weff, wqu, wqi, VU, VI, bv, out);
    }
}

// Round 6
// 162.131 us; speedup vs baseline: 1.6734x; 1.0926x over previous
//
#include <hip/hip_runtime.h>
#include <hip/hip_bf16.h>

typedef __bf16 bf16x8 __attribute__((ext_vector_type(8)));
typedef float f32x4 __attribute__((ext_vector_type(4)));
typedef unsigned short u16x8 __attribute__((ext_vector_type(8)));

__device__ __forceinline__ unsigned short f2bf(float f) {
    unsigned int u = __builtin_bit_cast(unsigned int, f);
    unsigned int r = (u + 0x7FFFu + ((u >> 16) & 1u)) >> 16;
    return (unsigned short)r;
}

__device__ __forceinline__ void load_lds_16(const void* g, void* lds) {
    __builtin_amdgcn_global_load_lds(
        (const __attribute__((address_space(1))) unsigned int*)g,
        (__attribute__((address_space(3))) unsigned int*)lds, 16, 0, 0);
}

// ---------- prep: fused conv_x (bx<6144) + weffB (bx<8448) + wq (rest) ----------
__global__ void prep_kernel(const float* __restrict__ x, unsigned short* __restrict__ xb,
                            const float* __restrict__ W, const float* __restrict__ A,
                            const float* __restrict__ B, unsigned short* __restrict__ weffB,
                            const float* __restrict__ uh, const float* __restrict__ ih,
                            const float* __restrict__ Wu, const float* __restrict__ Wi,
                            float* __restrict__ wqu, float* __restrict__ wqi) {
    int bx = blockIdx.x;
    int t = threadIdx.x;
    if (bx < 6144) {
        int i = bx * 256 + t;
        const float4* xp = (const float4*)x;
        float4 a = xp[i * 2];
        float4 c = xp[i * 2 + 1];
        u16x8 r;
        r[0] = f2bf(a.x); r[1] = f2bf(a.y); r[2] = f2bf(a.z); r[3] = f2bf(a.w);
        r[4] = f2bf(c.x); r[5] = f2bf(c.y); r[6] = f2bf(c.z); r[7] = f2bf(c.w);
        *(u16x8*)(xb + (size_t)i * 8) = r;
    } else if (bx < 8448) {
        int idx = bx - 6144;
        int o = idx / 3;
        int k = (idx % 3) * 256 + t;
        float acc = W[o * 768 + k];
#pragma unroll
        for (int r = 0; r < 8; ++r) acc += 2.0f * B[o * 8 + r] * A[r * 768 + k];
        weffB[o * 768 + k] = f2bf(acc);
    } else {
        int b2 = bx - 8448;
        int og = b2 % 192;
        int rest = b2 / 192;
        int b = rest & 63;
        int br = rest >> 6;
        int wave = t >> 6, lane = t & 63;
        int o = og * 4 + wave;
        const float* h = (br ? ih : uh) + b * 768;
        const float* Wrow = (br ? Wi : Wu) + (size_t)o * 768;
        const float4* hp = (const float4*)(h + lane * 12);
        const float4* wp = (const float4*)(Wrow + lane * 12);
        float s = 0.0f;
#pragma unroll
        for (int j = 0; j < 3; ++j) {
            float4 hv = hp[j], wv = wp[j];
            s += hv.x * wv.x + hv.y * wv.y + hv.z * wv.z + hv.w * wv.w;
        }
#pragma unroll
        for (int off = 32; off; off >>= 1) s += __shfl_down(s, off);
        if (lane == 0) (br ? wqi : wqu)[b * 768 + o] = s;
    }
}

// ---------- fused GEMM: out[b,s,o] = bias[o] + sum_k x[s,k]*(Weff[o,k] + K_b[k,o]) ----------
// Combined-B: per k-iter each thread loads its Weff chunk to REGISTERS (global,
// L2-hit, double-buffered across kk), adds the VALU-built K values, and writes ONE
// bf16 B-tile to LDS. One MFMA per fragment. A-tile streams via global_load_lds.
__global__ __launch_bounds__(256, 3) void gemm_fused_kernel(
    const unsigned short* __restrict__ Xb, const unsigned short* __restrict__ WeffB,
    const float* __restrict__ VU, const float* __restrict__ VI,
    const float* __restrict__ wqu, const float* __restrict__ wqi,
    const float* __restrict__ bias, float* __restrict__ out) {
    __shared__ __align__(16) unsigned short As[128 * 64];
    __shared__ __align__(16) unsigned short Bs[128 * 64];
    __shared__ __align__(16) unsigned int vui[32 * 26]; // [m][n pad26], (bf16(VU)<<16)|bf16(VI)
    __shared__ __align__(16) float wqs[32 * 8];          // [q][g][{u,i}]
    __shared__ float bias_s[128];
    const int tid = threadIdx.x;
    const int wave = tid >> 6, lane = tid & 63;
    const int id = blockIdx.x;            // nt*128 + b*2 + mt (same-A blocks = same XCD)
    const int nt = id >> 7, rem = id & 127, b = rem >> 1, mt = rem & 1;
    const int s0 = mt * 128, n0 = nt * 128;

    // ---- one-time staging ----
    for (int i = tid; i < 768; i += 256) {
        int n = i >> 5, m = i & 31;
        vui[m * 26 + n] = ((unsigned int)f2bf(VU[i]) << 16) | (unsigned int)f2bf(VI[i]);
    }
    {
        int q = tid >> 3, g = (tid >> 1) & 3, br = tid & 1;
        const float* wq = br ? wqi : wqu;
        wqs[tid] = wq[b * 768 + q * 24 + nt * 4 + g];
    }
    if (tid < 128) bias_s[tid] = bias[n0 + tid];
    __syncthreads();

    const unsigned short* Abase = Xb + (size_t)(b * 256 + s0) * 768;
    const unsigned short* Bbase = WeffB + (size_t)n0 * 768;
    const int wm = wave & 1, wn = wave >> 1;
    const int lrow = lane >> 3, lcp = lane & 7;      // A-DMA mapping
    const int rg = tid >> 3, cc = tid & 7;           // B-build: rows g*32+rg, chunk cc
    const int sl = cc ^ (rg & 7);                    // physical slot (same all g)
    const unsigned short* Wp0 = Bbase + (size_t)rg * 768 + cc * 8;

    f32x4 acc[4][4] = {};
    u16x8 wreg[4];
#pragma unroll
    for (int g = 0; g < 4; ++g) wreg[g] = *(const u16x8*)(Wp0 + (size_t)g * 32 * 768);

    for (int kk = 0; kk < 768; kk += 64) {
        // async DMA staging of As
#pragma unroll
        for (int u = 0; u < 4; ++u) {
            int tA = wave * 4 + u;
            int r = tA * 8 + lrow;
            int c = lcp ^ (r & 7);
            load_lds_16(Abase + (size_t)r * 768 + kk + c * 8, (void*)(As + tA * 512));
        }
        // K values for chunk cc: k = kb..kb+7, constant q, no n-wrap
        {
            int kb = kk + cc * 8;
            int q = (kb * 2731) >> 16;
            int n0c = kb - q * 24;                   // 0, 8, or 16
            const unsigned int* vp = &vui[rg * 26 + n0c];
            uint2 pv01 = *(const uint2*)(vp);
            uint2 pv23 = *(const uint2*)(vp + 2);
            uint2 pv45 = *(const uint2*)(vp + 4);
            uint2 pv67 = *(const uint2*)(vp + 6);
            unsigned int pv[8] = {pv01.x, pv01.y, pv23.x, pv23.y, pv45.x, pv45.y, pv67.x, pv67.y};
            float fu[8], fi[8];
#pragma unroll
            for (int j = 0; j < 8; ++j) {
                fu[j] = __builtin_bit_cast(float, pv[j] & 0xFFFF0000u);
                fi[j] = __builtin_bit_cast(float, pv[j] << 16);
            }
            const float4* wp4 = (const float4*)&wqs[q * 8];
            float4 wa = wp4[0], wb = wp4[1];         // {u0,i0,u1,i1},{u2,i2,u3,i3}
            float wu[4] = {wa.x, wa.z, wb.x, wb.z};
            float wi[4] = {wa.y, wa.w, wb.y, wb.w};
#pragma unroll
            for (int g = 0; g < 4; ++g) {
                u16x8 kv;
#pragma unroll
                for (int j = 0; j < 8; ++j) {
                    float wf = __builtin_bit_cast(float, (unsigned int)wreg[g][j] << 16);
                    float v = wf + fu[j] * wu[g];
                    v = v + fi[j] * wi[g];
                    kv[j] = (unsigned short)(__builtin_bit_cast(unsigned int, v) >> 16);
                }
                *(u16x8*)(Bs + (g * 32 + rg) * 64 + sl * 8) = kv;
            }
        }
        // register prefetch of next Weff chunk (drains with the A-DMA barrier wait)
        if (kk < 704) {
            const unsigned short* Wn = Wp0 + kk + 64;
#pragma unroll
            for (int g = 0; g < 4; ++g) wreg[g] = *(const u16x8*)(Wn + (size_t)g * 32 * 768);
        }
        __syncthreads();
#pragma unroll
        for (int h = 0; h < 2; ++h) {
            const int cb = h * 4 + (lane >> 4);
            const int rl = lane & 15;
            bf16x8 af[4], bw[4];
#pragma unroll
            for (int i = 0; i < 4; ++i) {
                int r = wm * 64 + i * 16 + rl;
                int c = cb ^ (r & 7);
                af[i] = *(const bf16x8*)(As + r * 64 + c * 8);
            }
#pragma unroll
            for (int j = 0; j < 4; ++j) {
                int r = wn * 64 + j * 16 + rl;
                int c = cb ^ (r & 7);
                bw[j] = *(const bf16x8*)(Bs + r * 64 + c * 8);
            }
#pragma unroll
            for (int i = 0; i < 4; ++i)
#pragma unroll
                for (int j = 0; j < 4; ++j)
                    acc[i][j] = __builtin_amdgcn_mfma_f32_16x16x32_bf16(af[i], bw[j], acc[i][j], 0, 0, 0);
        }
        __syncthreads();
    }

    // epilogue: C/D layout col=lane&15, row=(lane>>4)*4+reg
    const int cl = lane & 15, rq = lane >> 4;
#pragma unroll
    for (int j = 0; j < 4; ++j) {
        int nn = wn * 64 + j * 16 + cl;
        float bv = bias_s[nn];
#pragma unroll
        for (int i = 0; i < 4; ++i) {
            int mrow = s0 + wm * 64 + i * 16 + rq * 4;
            float* op = out + (size_t)(b * 256 + mrow) * 768 + n0 + nn;
#pragma unroll
            for (int g = 0; g < 4; ++g) op[(size_t)g * 768] = acc[i][j][g] + bv;
        }
    }
}

// ---------- fallback path (small ws) ----------
__global__ void weff_kernel(const float* __restrict__ W, const float* __restrict__ A,
                            const float* __restrict__ B, float* __restrict__ Weff) {
    int o = blockIdx.x / 3;
    int k = (blockIdx.x % 3) * 256 + threadIdx.x;
    float acc = W[o * 768 + k];
#pragma unroll
    for (int r = 0; r < 8; ++r) acc += 2.0f * B[o * 8 + r] * A[r * 768 + k];
    Weff[o * 768 + k] = acc;
}

__global__ void wq2_kernel(const float* __restrict__ uh, const float* __restrict__ ih,
                           const float* __restrict__ Wu, const float* __restrict__ Wi,
                           float* __restrict__ wqu, float* __restrict__ wqi) {
    int bx = blockIdx.x;
    int og = bx % 192;
    int rest = bx / 192;
    int b = rest & 63;
    int br = rest >> 6;
    int wave = threadIdx.x >> 6, lane = threadIdx.x & 63;
    int o = og * 4 + wave;
    const float* h = (br ? ih : uh) + b * 768;
    const float* Wrow = (br ? Wi : Wu) + (size_t)o * 768;
    const float4* hp = (const float4*)(h + lane * 12);
    const float4* wp = (const float4*)(Wrow + lane * 12);
    float s = 0.0f;
#pragma unroll
    for (int j = 0; j < 3; ++j) {
        float4 hv = hp[j], wv = wp[j];
        s += hv.x * wv.x + hv.y * wv.y + hv.z * wv.z + hv.w * wv.w;
    }
#pragma unroll
    for (int off = 32; off; off >>= 1) s += __shfl_down(s, off);
    if (lane == 0) (br ? wqi : wqu)[b * 768 + o] = s;
}

__global__ void naive_kernel(const float* __restrict__ x, const float* __restrict__ Weff,
                             const float* __restrict__ wqu, const float* __restrict__ wqi,
                             const float* __restrict__ VU, const float* __restrict__ VI,
                             const float* __restrict__ bias, float* __restrict__ out) {
    int bs_ = blockIdx.x / 3;
    int chunk = blockIdx.x % 3;
    int b = bs_ >> 8;
    __shared__ float xs[768];
    for (int i = threadIdx.x; i < 768; i += 256) xs[i] = x[(size_t)bs_ * 768 + i];
    __syncthreads();
    int o = chunk * 256 + threadIdx.x;
    int m = o & 31, l = o >> 5;
    float acc = bias[o];
    for (int q = 0; q < 32; ++q) {
        float wu = wqu[b * 768 + q * 24 + l];
        float wi = wqi[b * 768 + q * 24 + l];
#pragma unroll
        for (int n = 0; n < 24; ++n) {
            int k = q * 24 + n;
            float w = Weff[o * 768 + k] + VU[n * 32 + m] * wu + VI[n * 32 + m] * wi;
            acc += xs[k] * w;
        }
    }
    out[(size_t)bs_ * 768 + o] = acc;
}

extern "C" void kernel_launch(void* const* d_in, const int* in_sizes, int n_in,
                              void* d_out, int out_size, void* d_ws, size_t ws_size,
                              hipStream_t stream) {
    const float* x  = (const float*)d_in[0];
    const float* uh = (const float*)d_in[1];
    const float* ih = (const float*)d_in[2];
    const float* W  = (const float*)d_in[3];
    const float* bv = (const float*)d_in[4];
    const float* A  = (const float*)d_in[5];
    const float* B  = (const float*)d_in[6];
    const float* Wu = (const float*)d_in[7];
    const float* VU = (const float*)d_in[8];
    const float* Wi = (const float*)d_in[9];
    const float* VI = (const float*)d_in[10];
    float* out = (float*)d_out;

    const size_t off_xb   = 0;                        // 25,165,824 B
    const size_t off_weff = 25165824;                 // 1,179,648 B (bf16)
    const size_t off_wqu  = off_weff + 1179648;       // 196,608 B
    const size_t off_wqi  = off_wqu + 196608;
    const size_t need     = off_wqi + 196608;         // ~26.7 MB

    char* ws = (char*)d_ws;
    if (ws_size >= need) {
        unsigned short* xb    = (unsigned short*)(ws + off_xb);
        unsigned short* weffB = (unsigned short*)(ws + off_weff);
        float* wqu = (float*)(ws + off_wqu);
        float* wqi = (float*)(ws + off_wqi);
        prep_kernel<<<33024, 256, 0, stream>>>(x, xb, W, A, B, weffB, uh, ih, Wu, Wi, wqu, wqi);
        gemm_fused_kernel<<<768, 256, 0, stream>>>(xb, weffB, VU, VI, wqu, wqi, bv, out);
    } else {
        float* weff = (float*)ws;
        float* wqu  = weff + 589824;
        float* wqi  = wqu + 49152;
        weff_kernel<<<2304, 256, 0, stream>>>(W, A, B, weff);
        wq2_kernel<<<24576, 256, 0, stream>>>(uh, ih, Wu, Wi, wqu, wqi);
        naive_kernel<<<49152, 256, 0, stream>>>(x, weff, wqu, wqi, VU, VI, bv, out);
    }
}